// Round 2
// baseline (1789.776 us; speedup 1.0000x reference)
//
#include <hip/hip_runtime.h>
#include <hip/hip_bf16.h>
#include <math.h>

// Problem constants
#define SEQ 4096
#define LL  4097           // sequence + CLS
#define HDIM 32
#define FFD 2048
#define NLAYER 6
#define EPSLN 1e-5f
#define NCHUNK 16          // split-K chunks over keys
#define KPAD 4128          // keys 0..4096 padded to 129*32
#define QROWS 4160         // 65 * 64 query rows (pad rows zero)
#define XROWS 4160
#define FS 128             // FFN f-segment width
#define NSEG 8             // part2 segments
#define NBLK 512           // persistent blocks (2/CU guaranteed resident)
#define NWAVE 2048         // NBLK * 4 waves

#if __has_builtin(__builtin_amdgcn_exp2f)
#define EXP2 __builtin_amdgcn_exp2f
#else
#define EXP2 exp2f
#endif

#define QSCALE 0.7213475204444817f   // 0.5 * log2(e)

typedef short bf16x8 __attribute__((ext_vector_type(8)));
typedef float f32x4 __attribute__((ext_vector_type(4)));

__device__ __forceinline__ unsigned short f2b(float f) {   // fp32 -> bf16 RNE
  unsigned int b = __float_as_uint(f);
  b += 0x7FFFu + ((b >> 16) & 1u);
  return (unsigned short)(b >> 16);
}

__device__ __forceinline__ unsigned int pk_bf16(float a, float b) {
  __hip_bfloat162 h = __float22bfloat162_rn(make_float2(a, b));
  return *(unsigned int*)&h;
}

// Device-wide barrier: monotonic counter, release/acquire via __threadfence
// (agent-scope fence -> L2 writeback/invalidate on gfx950 for cross-XCD
// visibility). All NBLK blocks are co-resident by resource construction.
__device__ __forceinline__ void gsync(unsigned* bar, unsigned& tgt) {
  __syncthreads();
  tgt += NBLK;
  if (threadIdx.x == 0) {
    __threadfence();                 // release our writes
    atomicAdd(bar, 1u);
    while (__hip_atomic_load(bar, __ATOMIC_RELAXED, __HIP_MEMORY_SCOPE_AGENT) <
           tgt)
      __builtin_amdgcn_s_sleep(2);
    __threadfence();                 // acquire others' writes
  }
  __syncthreads();
}

// wave-level qkv projection + bf16 stores. y = this thread's (row,ch) value.
// Writes head h's K slot AND zeroes the sibling head's same slot (replaces
// the old full-buffer pre-zero, which would race with these stores when
// fused into one phase).
__device__ __forceinline__ void qkv_wave(float y, int row, bool ok, int lane,
    const float* __restrict__ qw, const float* __restrict__ qb,
    unsigned short* __restrict__ Qb, unsigned short* __restrict__ KB8,
    unsigned short* __restrict__ VB5) {
  int ch = lane & 31;
  float xv[32];
#pragma unroll
  for (int k = 0; k < 32; ++k) xv[k] = __shfl(y, (lane & 32) + k, 64);
#pragma unroll
  for (int t3 = 0; t3 < 3; ++t3) {
    int cc = t3 * 32 + ch;
    float acc = qb[cc];
#pragma unroll
    for (int k = 0; k < 32; ++k) acc = fmaf(xv[k], qw[cc * 32 + k], acc);
    if (ok) {
      int h = ch >> 2;
      if (t3 == 0) {
        Qb[(size_t)row * 32 + ch] = f2b(QSCALE * acc);
      } else if (t3 == 1) {
        KB8[((size_t)h * KPAD + row) * 8 + (ch & 7)] = f2b(acc);
        KB8[((size_t)(h ^ 1) * KPAD + row) * 8 + (ch & 7)] = 0;
      } else {
        int w = row & 31;
        int pos = ((w & 15) << 1) | (w >> 4);
        VB5[((size_t)h * 5 + (ch & 3)) * KPAD + (row & ~31) + pos] = f2b(acc);
      }
    }
  }
}

__global__ __launch_bounds__(256, 2) void k_mega(
    const float* __restrict__ data, const float* __restrict__ lin_w,
    const float* __restrict__ lin_b, const float* __restrict__ qkv_w,
    const float* __restrict__ qkv_b, const float* __restrict__ out_w,
    const float* __restrict__ out_b, const float* __restrict__ ln1_g,
    const float* __restrict__ ln1_b, const float* __restrict__ ff1_w,
    const float* __restrict__ ff1_b, const float* __restrict__ ff2_w,
    const float* __restrict__ ff2_b, const float* __restrict__ ln2_g,
    const float* __restrict__ ln2_b, const float* __restrict__ cls_w,
    const float* __restrict__ cls_b,
    float* __restrict__ X, unsigned short* __restrict__ Xb,
    unsigned short* __restrict__ Qb, unsigned short* __restrict__ KB8,
    unsigned short* __restrict__ VB5, unsigned short* __restrict__ W1B,
    unsigned short* __restrict__ W2B, float* __restrict__ APf,
    float* __restrict__ LP, float* __restrict__ out, unsigned* bar) {
  __shared__ unsigned short smem[4][5120];   // per-wave 10240 B scratch
  const int tid = threadIdx.x;
  const int wave = tid >> 6, lane = tid & 63;
  const int l16 = lane & 15, quad = lane >> 4;
  const int r = lane >> 5, ch = lane & 31;   // half-wave row / channel
  const unsigned wgid = blockIdx.x * 4 + wave;
  const int gid = blockIdx.x * 256 + tid;
  unsigned tgt = 0;

  // ============ phase 0a: setup (thread-stride, disjoint from embed) =======
  {
    const int NW = NLAYER * FFD * 32;
    for (int i = gid; i < NW; i += NBLK * 256) {
      W1B[i] = f2b(ff1_w[i]);
      W2B[i] = f2b(ff2_w[i]);
    }
    for (int i = gid; i < (QROWS - LL) * 32; i += NBLK * 256) {
      Qb[(size_t)LL * 32 + i] = 0;     // query pad rows
      Xb[(size_t)LL * 32 + i] = 0;     // ffnA A-operand pad rows
    }
    for (int i = gid; i < 8 * (KPAD - LL) * 8; i += NBLK * 256) {
      int hh = i / ((KPAD - LL) * 8);
      int rem = i % ((KPAD - LL) * 8);
      KB8[((size_t)hh * KPAD + LL + rem / 8) * 8 + (rem & 7)] = 0;
    }
    for (int i = gid; i < 8 * 5 * KPAD; i += NBLK * 256) {
      int col = i % KPAD;
      int dd = (i / KPAD) % 5;
      if (dd == 4) {
        int key = (col & ~31) + ((col & 1) << 4) + ((col & 31) >> 1);
        VB5[i] = (key <= 4096) ? 0x3F80 : 0;   // validity row
      } else if (col >= 4096 && (col & 31) != 0) {
        VB5[i] = 0;                            // pad-key V entries
      }
    }
  }
  // ============ phase 0b: embed + layer-0 qkv (wave items, 2 rows each) ====
  for (unsigned it = wgid; it < 2049; it += NWAVE) {
    int row = it * 2 + r;
    bool ok = row < LL;
    float val = 0.f;
    if (ok) {
      if (row == 0) {
        val = -1.0f;
      } else {
        int s = row - 1;
        float ts = data[s * 3 + 0];
        float f0 = data[s * 3 + 1];
        float f1 = data[s * 3 + 2];
        float lin = f0 * lin_w[ch * 2 + 0] + f1 * lin_w[ch * 2 + 1] + lin_b[ch];
        lin = fmaxf(lin, 0.0f);
        int tsi = (int)(ts / 100.0f);
        int j = ch >> 1;
        float aj = (float)(2 * j) * (float)(-0.28782313662425575);
        float divj = (float)exp((double)aj);
        float ang = (float)tsi * divj;
        float pe = (ch & 1) ? cosf(ang) : sinf(ang);
        val = lin + pe;
      }
      X[(size_t)row * HDIM + ch] = val;
    }
    qkv_wave(val, row, ok, lane, qkv_w, qkv_b, Qb, KB8, VB5);
  }
  gsync(bar, tgt);

  for (int l = 0; l < NLAYER; ++l) {
    // ================= attn phase: wave items (64q, head, chunk) ===========
    for (unsigned it = wgid; it < 65 * 8 * NCHUNK; it += NWAVE) {
      int c = it & 15;
      int h = (it >> 4) & 7;
      int q64 = it >> 7;
      int q0 = q64 * 64;
      int kb0 = c * 256;
      int nkb = (c == NCHUNK - 1) ? 9 : 8;
      const unsigned short* KBh = KB8 + (size_t)h * KPAD * 8;
      const unsigned short* VBh = VB5 + (size_t)h * 5 * KPAD;
      const bool klq = (quad == (h >> 1));   // only this quad carries K data
      const bool vlq = (l16 < 5);            // only V rows 0..4 nonzero

      bf16x8 aq[4];
#pragma unroll
      for (int t = 0; t < 4; ++t)
        aq[t] =
            *(const bf16x8*)&Qb[(size_t)(q0 + t * 16 + l16) * 32 + quad * 8];

      const bf16x8 zb = {0, 0, 0, 0, 0, 0, 0, 0};
      f32x4 acc0[4], acc1[4];
#pragma unroll
      for (int t = 0; t < 4; ++t) {
        acc0[t] = (f32x4){0.f, 0.f, 0.f, 0.f};
        acc1[t] = (f32x4){0.f, 0.f, 0.f, 0.f};
      }
      unsigned short* P0 = &smem[wave][0];
      unsigned short* P1 = &smem[wave][2560];

      auto step = [&](int k0, unsigned short* P, f32x4* acc) {
        bf16x8 bk0 = klq ? *(const bf16x8*)&KBh[(size_t)(k0 + l16) * 8] : zb;
        bf16x8 bk1 =
            klq ? *(const bf16x8*)&KBh[(size_t)(k0 + 16 + l16) * 8] : zb;
        f32x4 z = {0.f, 0.f, 0.f, 0.f};
        f32x4 s0[4], s1[4];
#pragma unroll
        for (int t = 0; t < 4; ++t) {
          s0[t] = __builtin_amdgcn_mfma_f32_16x16x32_bf16(aq[t], bk0, z, 0, 0, 0);
          s1[t] = __builtin_amdgcn_mfma_f32_16x16x32_bf16(aq[t], bk1, z, 0, 0, 0);
        }
#pragma unroll
        for (int t = 0; t < 4; ++t)
#pragma unroll
          for (int reg = 0; reg < 4; ++reg) {
            int rw = quad * 4 + reg;
            *(unsigned int*)&P[t * 640 + rw * 40 + l16 * 2] =
                pk_bf16(EXP2(s0[t][reg]), EXP2(s1[t][reg]));
          }
        bf16x8 bv = zb;
        if (vlq)
          bv = *(const bf16x8*)&VBh[(size_t)l16 * KPAD + k0 + quad * 8];
        // wave-private LDS transpose (lockstep wave, in-order DS: no barrier)
#pragma unroll
        for (int t = 0; t < 4; ++t) {
          bf16x8 a2 = *(const bf16x8*)&P[t * 640 + l16 * 40 + quad * 8];
          acc[t] =
              __builtin_amdgcn_mfma_f32_16x16x32_bf16(a2, bv, acc[t], 0, 0, 0);
        }
      };

      int kb = 0;
      for (; kb + 2 <= nkb; kb += 2) {
        step(kb0 + kb * 32, P0, acc0);
        step(kb0 + (kb + 1) * 32, P1, acc1);
      }
      if (kb < nkb) step(kb0 + kb * 32, P0, acc0);

      size_t base = ((size_t)c * 8 + h) * LL;
#pragma unroll
      for (int t = 0; t < 4; ++t) {
        f32x4 a = acc0[t] + acc1[t];
#pragma unroll
        for (int reg = 0; reg < 4; ++reg) {
          int q = q0 + t * 16 + quad * 4 + reg;
          if (q < LL) {
            if (l16 < 4) APf[(base + q) * 4 + l16] = a[reg];
            else if (l16 == 4) LP[base + q] = a[reg];
          }
        }
      }
    }
    gsync(bar, tgt);

    // ======= oproj phase: sum split-K + o-proj + residual + LN1 ============
    {
      const float* owl = out_w + (size_t)l * 32 * 32;
      const float* obl = out_b + (size_t)l * 32;
      const float* g1 = ln1_g + (size_t)l * 32;
      const float* bl1 = ln1_b + (size_t)l * 32;
      for (unsigned it = wgid; it < 2049; it += NWAVE) {
        int row = it * 2 + r;
        bool ok = row < LL;
        int hh = ch >> 2, dd = ch & 3;
        float Ls = 0.f, As = 0.f;
        if (ok) {
#pragma unroll
          for (int c = 0; c < NCHUNK; ++c) {
            size_t idx = ((size_t)c * 8 + hh) * LL + row;
            Ls += LP[idx];
            As += APf[idx * 4 + dd];
          }
        }
        float os = ok ? As / Ls : 0.f;
        float acc = 0.f;
#pragma unroll
        for (int k = 0; k < 32; ++k)
          acc = fmaf(__shfl(os, (lane & 32) + k, 64), owl[ch * 32 + k], acc);
        float val = ok ? (X[(size_t)row * HDIM + ch] + acc + obl[ch]) : 0.f;
        float mean = val;
#pragma unroll
        for (int off = 16; off > 0; off >>= 1) mean += __shfl_xor(mean, off, 32);
        mean *= (1.f / 32.f);
        float d2 = val - mean;
        float var = d2 * d2;
#pragma unroll
        for (int off = 16; off > 0; off >>= 1) var += __shfl_xor(var, off, 32);
        var *= (1.f / 32.f);
        float y = d2 / sqrtf(var + EPSLN) * g1[ch] + bl1[ch];
        if (ok) {
          X[(size_t)row * HDIM + ch] = y;
          Xb[(size_t)row * HDIM + ch] = f2b(y);
        }
      }
    }
    gsync(bar, tgt);

    // ======= ffnA phase: wave items (16 rows, 2 f-segments) ================
    {
      const unsigned short* w1l = W1B + (size_t)l * FFD * 32;
      const unsigned short* w2l = W2B + (size_t)l * FFD * 32;
      const float* fb1 = ff1_b + (size_t)l * FFD;
      for (unsigned it = wgid; it < 260 * 8; it += NWAVE) {
        int y8 = it & 7;
        int rg = it >> 3;
        unsigned short* Fs = &smem[wave][0];   // wave-private 16x136 tile
        bf16x8 a1 =
            *(const bf16x8*)&Xb[(size_t)(rg * 16 + l16) * 32 + quad * 8];
        f32x4 facc[2] = {{0.f, 0.f, 0.f, 0.f}, {0.f, 0.f, 0.f, 0.f}};
#pragma unroll
        for (int sg = 0; sg < 2; ++sg) {
          int f0 = (y8 * 2 + sg) * FS;
          f32x4 c1[8];
#pragma unroll
          for (int t = 0; t < 8; ++t) {
            bf16x8 b = *(const bf16x8*)&w1l[(size_t)(f0 + t * 16 + l16) * 32 +
                                            quad * 8];
            f32x4 z = {0.f, 0.f, 0.f, 0.f};
            c1[t] = __builtin_amdgcn_mfma_f32_16x16x32_bf16(a1, b, z, 0, 0, 0);
          }
#pragma unroll
          for (int t = 0; t < 8; ++t) {
            float bb = fb1[f0 + t * 16 + l16];
#pragma unroll
            for (int reg = 0; reg < 4; ++reg) {
              float v = fmaxf(c1[t][reg] + bb, 0.f);
              Fs[(quad * 4 + reg) * 136 + t * 16 + l16] = f2b(v);
            }
          }
          // wave-private transpose via LDS; in-order DS -> no barrier
#pragma unroll
          for (int kt = 0; kt < 4; ++kt) {
            bf16x8 a2 =
                *(const bf16x8*)&Fs[(size_t)l16 * 136 + kt * 32 + quad * 8];
#pragma unroll
            for (int u = 0; u < 2; ++u) {
              bf16x8 b = *(const bf16x8*)&w2l[(size_t)(u * 16 + l16) * FFD +
                                              f0 + kt * 32 + quad * 8];
              facc[u] =
                  __builtin_amdgcn_mfma_f32_16x16x32_bf16(a2, b, facc[u], 0, 0, 0);
            }
          }
        }
#pragma unroll
        for (int u = 0; u < 2; ++u)
#pragma unroll
          for (int reg = 0; reg < 4; ++reg) {
            int rrow = rg * 16 + quad * 4 + reg;
            if (rrow < LL)
              APf[((size_t)y8 * LL + rrow) * 32 + u * 16 + l16] =
                  facc[u][reg];   // part2 aliases AP (AP dead post-oproj)
          }
      }
    }
    gsync(bar, tgt);

    // ======= ffnB phase: combine + residual + LN2 + next qkv / classifier ==
    {
      const float* fb2 = ff2_b + (size_t)l * 32;
      const float* g2 = ln2_g + (size_t)l * 32;
      const float* bl2 = ln2_b + (size_t)l * 32;
      bool lastl = (l == NLAYER - 1);
      const float* qwn = qkv_w + (size_t)(lastl ? 0 : (l + 1)) * 96 * 32;
      const float* qbn = qkv_b + (size_t)(lastl ? 0 : (l + 1)) * 96;
      for (unsigned it = wgid; it < 2049; it += NWAVE) {
        int row = it * 2 + r;
        bool ok = row < LL;
        float s = 0.f;
        if (ok) {
#pragma unroll
          for (int q = 0; q < NSEG; ++q)
            s += APf[((size_t)q * LL + row) * 32 + ch];
        }
        float val = ok ? (X[(size_t)row * HDIM + ch] + s + fb2[ch]) : 0.f;
        float mean = val;
#pragma unroll
        for (int off = 16; off > 0; off >>= 1) mean += __shfl_xor(mean, off, 32);
        mean *= (1.f / 32.f);
        float d2 = val - mean;
        float var = d2 * d2;
#pragma unroll
        for (int off = 16; off > 0; off >>= 1) var += __shfl_xor(var, off, 32);
        var *= (1.f / 32.f);
        float y = d2 / sqrtf(var + EPSLN) * g2[ch] + bl2[ch];
        if (ok) X[(size_t)row * HDIM + ch] = y;
        if (lastl) {
          if (it == 0 && r == 0) {   // row 0 = CLS
            float t = y * cls_w[ch];
#pragma unroll
            for (int off = 16; off > 0; off >>= 1) t += __shfl_xor(t, off, 32);
            if (ch == 0) out[0] = 1.f / (1.f + expf(-(t + cls_b[0])));
          }
        } else {
          qkv_wave(y, row, ok, lane, qwn, qbn, Qb, KB8, VB5);
        }
      }
    }
    if (l + 1 < NLAYER) gsync(bar, tgt);
  }
}

extern "C" void kernel_launch(void* const* d_in, const int* in_sizes, int n_in,
                              void* d_out, int out_size, void* d_ws,
                              size_t ws_size, hipStream_t stream) {
  const float* data  = (const float*)d_in[0];
  const float* lin_w = (const float*)d_in[1];
  const float* lin_b = (const float*)d_in[2];
  const float* qkv_w = (const float*)d_in[3];
  const float* qkv_b = (const float*)d_in[4];
  const float* out_w = (const float*)d_in[5];
  const float* out_b = (const float*)d_in[6];
  const float* ln1_g = (const float*)d_in[7];
  const float* ln1_b = (const float*)d_in[8];
  const float* ff1_w = (const float*)d_in[9];
  const float* ff1_b = (const float*)d_in[10];
  const float* ff2_w = (const float*)d_in[11];
  const float* ff2_b = (const float*)d_in[12];
  const float* ln2_g = (const float*)d_in[13];
  const float* ln2_b = (const float*)d_in[14];
  const float* cls_w = (const float*)d_in[15];
  const float* cls_b = (const float*)d_in[16];

  char* wsb = (char*)d_ws;
  unsigned* bar = (unsigned*)wsb;                       // 256 B barrier area
  float* X = (float*)(wsb + 256);                       // LL*32 fp32
  unsigned short* Xb  = (unsigned short*)(X + (size_t)LL * 32);
  unsigned short* Qb  = Xb + (size_t)XROWS * 32;
  unsigned short* KB8 = Qb + (size_t)QROWS * 32;        // 8*KPAD*8
  unsigned short* VB5 = KB8 + (size_t)8 * KPAD * 8;     // 8*5*KPAD
  unsigned short* W1B = VB5 + (size_t)8 * 5 * KPAD;     // NL*FFD*32
  unsigned short* W2B = W1B + (size_t)NLAYER * FFD * 32;
  float* APf = (float*)(((size_t)(W2B + (size_t)NLAYER * FFD * 32) + 15) &
                        ~(size_t)15);                   // NCHUNK*8*LL float4
  float* LP = APf + (size_t)NCHUNK * 8 * LL * 4;

  hipMemsetAsync(bar, 0, 256, stream);
  k_mega<<<NBLK, 256, 0, stream>>>(
      data, lin_w, lin_b, qkv_w, qkv_b, out_w, out_b, ln1_g, ln1_b, ff1_w,
      ff1_b, ff2_w, ff2_b, ln2_g, ln2_b, cls_w, cls_b, X, Xb, Qb, KB8, VB5,
      W1B, W2B, APf, LP, (float*)d_out, bar);
}

// Round 3
// 522.781 us; speedup vs baseline: 3.4236x; 3.4236x over previous
//
#include <hip/hip_runtime.h>
#include <hip/hip_bf16.h>
#include <math.h>

// Problem constants
#define SEQ 4096
#define LL  4097           // sequence + CLS
#define HDIM 32
#define FFD 2048
#define NLAYER 6
#define EPSLN 1e-5f
#define NCHUNK 16          // split-K chunks over keys
#define KPAD 4128          // keys 0..4096 padded to 129*32
#define QROWS 4352         // 17 blocks * 4 waves * 64 queries
#define RB 16              // fused-kernel row block

#if __has_builtin(__builtin_amdgcn_exp2f)
#define EXP2 __builtin_amdgcn_exp2f
#else
#define EXP2 exp2f
#endif

#define QSCALE 0.7213475204444817f   // 0.5 * log2(e)

typedef short bf16x8 __attribute__((ext_vector_type(8)));
typedef float f32x4 __attribute__((ext_vector_type(4)));

__device__ __forceinline__ unsigned short f2b(float f) {   // fp32 -> bf16 RNE
  unsigned int b = __float_as_uint(f);
  b += 0x7FFFu + ((b >> 16) & 1u);
  return (unsigned short)(b >> 16);
}

__device__ __forceinline__ unsigned int pk_bf16(float a, float b) {
  __hip_bfloat162 h = __float22bfloat162_rn(make_float2(a, b));
  return *(unsigned int*)&h;
}

// Buffers:
//  Qb  [QROWS][32]  bf16, pre-scaled by QSCALE (pad rows zero)
//  KB8 [8][KPAD][8] bf16 — head h's K dims at slots (4h+d)&7 (h even: 0..3,
//      h odd: 4..7); the other 4 slots and pad rows are zeroed ONCE in k_init
//      and never dirtied (per-layer qkv always writes the same slots).
//  VB5 [8][5][KPAD] bf16, rows 0..3 = V dims (permuted key order), row 4 =
//      validity ones. Key permutation within 32-blocks:
//      pos = ((w&15)<<1) | (w>>4). Pad positions init'd once (disjoint from
//      per-layer qkv writes).
//  LP[(c*8+h)*LL+q] float, APf[((c*8+h)*LL+q)*4+d] — split-K partials.

// wave-level qkv projection + bf16 stores. y = this thread's (row,ch) value.
__device__ __forceinline__ void qkv_wave(float y, int row, bool ok, int lane,
    const float* __restrict__ qw, const float* __restrict__ qb,
    unsigned short* __restrict__ Qb, unsigned short* __restrict__ KB8,
    unsigned short* __restrict__ VB5) {
  int ch = lane & 31;
  float xv[32];
#pragma unroll
  for (int k = 0; k < 32; ++k) xv[k] = __shfl(y, (lane & 32) + k, 64);
#pragma unroll
  for (int t3 = 0; t3 < 3; ++t3) {
    int cc = t3 * 32 + ch;
    float acc = qb[cc];
#pragma unroll
    for (int k = 0; k < 32; ++k) acc = fmaf(xv[k], qw[cc * 32 + k], acc);
    if (ok) {
      int h = ch >> 2;
      if (t3 == 0) {
        Qb[(size_t)row * 32 + ch] = f2b(QSCALE * acc);
      } else if (t3 == 1) {
        KB8[((size_t)h * KPAD + row) * 8 + (ch & 7)] = f2b(acc);
      } else {
        int w = row & 31;
        int pos = ((w & 15) << 1) | (w >> 4);
        VB5[((size_t)h * 5 + (ch & 3)) * KPAD + (row & ~31) + pos] = f2b(acc);
      }
    }
  }
}

// ---- init: weight cvt + pad zeroing + embed + layer-0 qkv (all disjoint) ---
__global__ __launch_bounds__(256) void k_init(const float* __restrict__ data,
    const float* __restrict__ lin_w, const float* __restrict__ lin_b,
    const float* __restrict__ qkv_w, const float* __restrict__ qkv_b,
    const float* __restrict__ ff1_w, const float* __restrict__ ff2_w,
    float* __restrict__ X, unsigned short* __restrict__ Qb,
    unsigned short* __restrict__ KB8, unsigned short* __restrict__ VB5,
    unsigned short* __restrict__ W1B, unsigned short* __restrict__ W2B) {
  int gid = blockIdx.x * 256 + threadIdx.x;
  int gsz = gridDim.x * 256;
  const int NW = NLAYER * FFD * 32;
  for (int i = gid; i < NW; i += gsz) {
    W1B[i] = f2b(ff1_w[i]);
    W2B[i] = f2b(ff2_w[i]);
  }
  for (int i = gid; i < (QROWS - LL) * 32; i += gsz)
    Qb[(size_t)LL * 32 + i] = 0;                    // query pad rows
  for (int i = gid; i < 8 * (KPAD - LL) * 8; i += gsz) {
    int hh = i / ((KPAD - LL) * 8);
    int rem = i % ((KPAD - LL) * 8);
    KB8[((size_t)hh * KPAD + LL) * 8 + rem] = 0;    // K pad rows
  }
  for (int i = gid; i < 8 * LL * 4; i += gsz) {     // K unwritten slots
    int hh = i / (LL * 4);
    int rem = i % (LL * 4);
    int rr = rem >> 2, s = rem & 3;
    int slot = (hh & 1) ? s : 4 + s;
    KB8[((size_t)hh * KPAD + rr) * 8 + slot] = 0;
  }
  for (int i = gid; i < 8 * 5 * KPAD; i += gsz) {
    int col = i % KPAD;
    int dd = (i / KPAD) % 5;
    if (dd == 4) {
      int key = (col & ~31) + ((col & 1) << 4) + ((col & 31) >> 1);
      VB5[i] = (key <= 4096) ? 0x3F80 : 0;          // validity row
    } else if (col > 4096) {
      VB5[i] = 0;                                   // pad-key V entries
    }
  }
  // embed + layer-0 qkv: wave items, 2 rows each
  int wave = threadIdx.x >> 6, lane = threadIdx.x & 63;
  int r = lane >> 5, ch = lane & 31;
  unsigned wgid = blockIdx.x * 4 + wave;
  for (unsigned it = wgid; it < 2049; it += gridDim.x * 4) {
    int row = it * 2 + r;
    bool ok = row < LL;
    float val = 0.f;
    if (ok) {
      if (row == 0) {
        val = -1.0f;
      } else {
        int s = row - 1;
        float ts = data[s * 3 + 0];
        float f0 = data[s * 3 + 1];
        float f1 = data[s * 3 + 2];
        float lin = f0 * lin_w[ch * 2 + 0] + f1 * lin_w[ch * 2 + 1] + lin_b[ch];
        lin = fmaxf(lin, 0.0f);
        int tsi = (int)(ts / 100.0f);
        int j = ch >> 1;
        float aj = (float)(2 * j) * (float)(-0.28782313662425575);
        float divj = (float)exp((double)aj);
        float ang = (float)tsi * divj;
        float pe = (ch & 1) ? cosf(ang) : sinf(ang);
        val = lin + pe;
      }
      X[(size_t)row * HDIM + ch] = val;
    }
    qkv_wave(val, row, ok, lane, qkv_w, qkv_b, Qb, KB8, VB5);
  }
}

// ---- attention via MFMA, masked K/V loads + 4 q-tiles per wave -------------
// grid (17, NHEAD, NCHUNK). Block = 4 waves; wave owns 4 q-tiles (64 queries).
__global__ __launch_bounds__(256, 3) void k_attn(
    const unsigned short* __restrict__ Qb, const unsigned short* __restrict__ KB8,
    const unsigned short* __restrict__ VB5, float* __restrict__ LP,
    float* __restrict__ APf) {
  __shared__ unsigned short Pt[4][8][16 * 40];
  int tid = threadIdx.x;
  int wave = tid >> 6, lane = tid & 63;
  int l16 = lane & 15, quad = lane >> 4;
  int h = blockIdx.y, c = blockIdx.z;
  int q0 = (blockIdx.x * 4 + wave) * 64;
  int kb0 = c * 256;
  int nkb = (c == NCHUNK - 1) ? 9 : 8;

  const unsigned short* KBh = KB8 + (size_t)h * KPAD * 8;
  const unsigned short* VBh = VB5 + (size_t)h * 5 * KPAD;
  const bool kl = (quad == (h >> 1));   // only this quad carries K data
  const bool vl = (l16 < 5);            // only V rows 0..4 are nonzero

  bf16x8 aq[4];
#pragma unroll
  for (int t = 0; t < 4; ++t)
    aq[t] = *(const bf16x8*)&Qb[(size_t)(q0 + t * 16 + l16) * 32 + quad * 8];

  const bf16x8 zb = {0, 0, 0, 0, 0, 0, 0, 0};
  f32x4 acc0[4], acc1[4];
#pragma unroll
  for (int t = 0; t < 4; ++t) {
    acc0[t] = (f32x4){0.f, 0.f, 0.f, 0.f};
    acc1[t] = (f32x4){0.f, 0.f, 0.f, 0.f};
  }

  auto step = [&](int k0, unsigned short* P, f32x4* acc) {
    bf16x8 bk0 = kl ? *(const bf16x8*)&KBh[(size_t)(k0 + l16) * 8] : zb;
    bf16x8 bk1 = kl ? *(const bf16x8*)&KBh[(size_t)(k0 + 16 + l16) * 8] : zb;
    f32x4 z = {0.f, 0.f, 0.f, 0.f};
    f32x4 s0[4], s1[4];
#pragma unroll
    for (int t = 0; t < 4; ++t) {
      s0[t] = __builtin_amdgcn_mfma_f32_16x16x32_bf16(aq[t], bk0, z, 0, 0, 0);
      s1[t] = __builtin_amdgcn_mfma_f32_16x16x32_bf16(aq[t], bk1, z, 0, 0, 0);
    }
#pragma unroll
    for (int t = 0; t < 4; ++t)
#pragma unroll
      for (int reg = 0; reg < 4; ++reg) {
        int row = quad * 4 + reg;
        *(unsigned int*)&P[t * 640 + row * 40 + l16 * 2] =
            pk_bf16(EXP2(s0[t][reg]), EXP2(s1[t][reg]));
      }
    bf16x8 bv = zb;
    if (vl) bv = *(const bf16x8*)&VBh[(size_t)l16 * KPAD + k0 + quad * 8];
    // wave-private LDS transpose (lockstep wave: no barrier needed)
#pragma unroll
    for (int t = 0; t < 4; ++t) {
      bf16x8 a2 = *(const bf16x8*)&P[t * 640 + l16 * 40 + quad * 8];
      acc[t] = __builtin_amdgcn_mfma_f32_16x16x32_bf16(a2, bv, acc[t], 0, 0, 0);
    }
  };

  int kb = 0;
  for (; kb + 2 <= nkb; kb += 2) {
    step(kb0 + kb * 32, &Pt[wave][0][0], acc0);
    step(kb0 + (kb + 1) * 32, &Pt[wave][4][0], acc1);
  }
  if (kb < nkb) step(kb0 + kb * 32, &Pt[wave][0][0], acc0);

  size_t base = ((size_t)c * 8 + h) * LL;
#pragma unroll
  for (int t = 0; t < 4; ++t) {
    f32x4 a = acc0[t] + acc1[t];
#pragma unroll
    for (int reg = 0; reg < 4; ++reg) {
      int q = q0 + t * 16 + quad * 4 + reg;
      if (q < LL) {
        if (l16 < 4) APf[(base + q) * 4 + l16] = a[reg];
        else if (l16 == 4) LP[base + q] = a[reg];
      }
    }
  }
}

// ---- fused per-16-row block: oproj+LN1 -> full FFN -> LN2 -> qkv/cls -------
// grid (257). Waves each own a 512-wide f-slice; GEMM2 partials reduced in
// LDS with one __syncthreads. FFN weights (256 KB/layer) are L2-resident.
__global__ __launch_bounds__(256) void k_fused(const float* __restrict__ LP,
    const float* __restrict__ APf, float* __restrict__ X,
    const float* __restrict__ ow, const float* __restrict__ ob,
    const float* __restrict__ g1, const float* __restrict__ b1ln,
    const unsigned short* __restrict__ w1l, const float* __restrict__ fb1,
    const unsigned short* __restrict__ w2l, const float* __restrict__ fb2,
    const float* __restrict__ g2, const float* __restrict__ b2ln,
    const float* __restrict__ qw, const float* __restrict__ qb,
    unsigned short* __restrict__ Qb, unsigned short* __restrict__ KB8,
    unsigned short* __restrict__ VB5, int do_qkv,
    const float* __restrict__ cw, const float* __restrict__ cb,
    float* __restrict__ out) {
  __shared__ unsigned short Xa[RB * 32];      // bf16 LN1 out (GEMM1 A-tile)
  __shared__ float Y1[RB * 32];               // fp32 LN1 out (FFN residual)
  __shared__ unsigned short Fs[4][16 * 136];  // per-wave transpose buffers
  __shared__ float Pr[4][RB * 33];            // per-wave GEMM2 partials
  int tid = threadIdx.x;
  int wave = tid >> 6, lane = tid & 63;
  int l16 = lane & 15, quad = lane >> 4;
  int r = lane >> 5, ch = lane & 31;
  int r0 = blockIdx.x * RB;

  // Phase A: split-K combine + o-proj + residual + LN1 (rows r0..r0+15)
#pragma unroll
  for (int it = 0; it < 2; ++it) {
    int rloc = wave * 4 + it * 2 + r;
    int row = r0 + rloc;
    bool ok = row < LL;
    int hh = ch >> 2, dd = ch & 3;
    float Ls = 0.f, As = 0.f;
    if (ok) {
#pragma unroll
      for (int c = 0; c < NCHUNK; ++c) {
        size_t idx = ((size_t)c * 8 + hh) * LL + row;
        Ls += LP[idx];
        As += APf[idx * 4 + dd];
      }
    }
    float os = ok ? As / Ls : 0.f;
    float acc = 0.f;
#pragma unroll
    for (int k = 0; k < 32; ++k)
      acc = fmaf(__shfl(os, (lane & 32) + k, 64), ow[ch * 32 + k], acc);
    float val = ok ? (X[(size_t)row * HDIM + ch] + acc + ob[ch]) : 0.f;
    float mean = val;
#pragma unroll
    for (int off = 16; off > 0; off >>= 1) mean += __shfl_xor(mean, off, 32);
    mean *= (1.f / 32.f);
    float d2 = val - mean;
    float var = d2 * d2;
#pragma unroll
    for (int off = 16; off > 0; off >>= 1) var += __shfl_xor(var, off, 32);
    var *= (1.f / 32.f);
    float y = d2 / sqrtf(var + EPSLN) * g1[ch] + b1ln[ch];
    Y1[rloc * 32 + ch] = y;
    Xa[rloc * 32 + ch] = f2b(y);
  }
  __syncthreads();

  // Phase B: FFN over this wave's 512-wide f-slice (wave-private transpose)
  bf16x8 a1 = *(const bf16x8*)&Xa[l16 * 32 + quad * 8];
  f32x4 acc2[2] = {{0.f, 0.f, 0.f, 0.f}, {0.f, 0.f, 0.f, 0.f}};
  int fs0 = wave * 512;
#pragma unroll
  for (int fc = 0; fc < 4; ++fc) {
    int f0 = fs0 + fc * 128;
    f32x4 c1[8];
#pragma unroll
    for (int t = 0; t < 8; ++t) {
      bf16x8 b =
          *(const bf16x8*)&w1l[(size_t)(f0 + t * 16 + l16) * 32 + quad * 8];
      f32x4 z = {0.f, 0.f, 0.f, 0.f};
      c1[t] = __builtin_amdgcn_mfma_f32_16x16x32_bf16(a1, b, z, 0, 0, 0);
    }
#pragma unroll
    for (int t = 0; t < 8; ++t) {
      float bb = fb1[f0 + t * 16 + l16];
#pragma unroll
      for (int reg = 0; reg < 4; ++reg) {
        float v = fmaxf(c1[t][reg] + bb, 0.f);
        Fs[wave][(quad * 4 + reg) * 136 + t * 16 + l16] = f2b(v);
      }
    }
    // in-order DS within lockstep wave: no barrier needed
#pragma unroll
    for (int kt = 0; kt < 4; ++kt) {
      bf16x8 a2 = *(const bf16x8*)&Fs[wave][l16 * 136 + kt * 32 + quad * 8];
#pragma unroll
      for (int u = 0; u < 2; ++u) {
        bf16x8 b = *(const bf16x8*)&w2l[(size_t)(u * 16 + l16) * FFD + f0 +
                                        kt * 32 + quad * 8];
        acc2[u] = __builtin_amdgcn_mfma_f32_16x16x32_bf16(a2, b, acc2[u], 0, 0, 0);
      }
    }
  }
#pragma unroll
  for (int u = 0; u < 2; ++u)
#pragma unroll
    for (int reg = 0; reg < 4; ++reg)
      Pr[wave][(quad * 4 + reg) * 33 + u * 16 + l16] = acc2[u][reg];
  __syncthreads();

  // Phase C: reduce wave partials + residual + LN2 + next qkv / classifier
#pragma unroll
  for (int it = 0; it < 2; ++it) {
    int rloc = wave * 4 + it * 2 + r;
    int row = r0 + rloc;
    bool ok = row < LL;
    float s = Pr[0][rloc * 33 + ch] + Pr[1][rloc * 33 + ch] +
              Pr[2][rloc * 33 + ch] + Pr[3][rloc * 33 + ch];
    float val = ok ? (Y1[rloc * 32 + ch] + s + fb2[ch]) : 0.f;
    float mean = val;
#pragma unroll
    for (int off = 16; off > 0; off >>= 1) mean += __shfl_xor(mean, off, 32);
    mean *= (1.f / 32.f);
    float d2 = val - mean;
    float var = d2 * d2;
#pragma unroll
    for (int off = 16; off > 0; off >>= 1) var += __shfl_xor(var, off, 32);
    var *= (1.f / 32.f);
    float y = d2 / sqrtf(var + EPSLN) * g2[ch] + b2ln[ch];
    if (ok) X[(size_t)row * HDIM + ch] = y;
    if (do_qkv) {
      qkv_wave(y, row, ok, lane, qw, qb, Qb, KB8, VB5);
    } else if (blockIdx.x == 0 && wave == 0 && it == 0 && r == 0) {
      // row 0 = CLS
      float t = y * cw[ch];
#pragma unroll
      for (int off = 16; off > 0; off >>= 1) t += __shfl_xor(t, off, 32);
      if (ch == 0) out[0] = 1.f / (1.f + expf(-(t + cb[0])));
    }
  }
}

extern "C" void kernel_launch(void* const* d_in, const int* in_sizes, int n_in,
                              void* d_out, int out_size, void* d_ws,
                              size_t ws_size, hipStream_t stream) {
  const float* data  = (const float*)d_in[0];
  const float* lin_w = (const float*)d_in[1];
  const float* lin_b = (const float*)d_in[2];
  const float* qkv_w = (const float*)d_in[3];
  const float* qkv_b = (const float*)d_in[4];
  const float* out_w = (const float*)d_in[5];
  const float* out_b = (const float*)d_in[6];
  const float* ln1_g = (const float*)d_in[7];
  const float* ln1_b = (const float*)d_in[8];
  const float* ff1_w = (const float*)d_in[9];
  const float* ff1_b = (const float*)d_in[10];
  const float* ff2_w = (const float*)d_in[11];
  const float* ff2_b = (const float*)d_in[12];
  const float* ln2_g = (const float*)d_in[13];
  const float* ln2_b = (const float*)d_in[14];
  const float* cls_w = (const float*)d_in[15];
  const float* cls_b = (const float*)d_in[16];

  char* wsb = (char*)d_ws;
  float* X = (float*)wsb;                               // LL*32 fp32
  unsigned short* Qb  = (unsigned short*)(X + (size_t)LL * 32);
  unsigned short* KB8 = Qb + (size_t)QROWS * 32;        // 8*KPAD*8
  unsigned short* VB5 = KB8 + (size_t)8 * KPAD * 8;     // 8*5*KPAD
  unsigned short* W1B = VB5 + (size_t)8 * 5 * KPAD;     // NL*FFD*32
  unsigned short* W2B = W1B + (size_t)NLAYER * FFD * 32;
  float* APf = (float*)(((size_t)(W2B + (size_t)NLAYER * FFD * 32) + 15) &
                        ~(size_t)15);                   // NCHUNK*8*LL*4
  float* LP = APf + (size_t)NCHUNK * 8 * LL * 4;

  k_init<<<1024, 256, 0, stream>>>(data, lin_w, lin_b, qkv_w, qkv_b,
                                   ff1_w, ff2_w, X, Qb, KB8, VB5, W1B, W2B);
  for (int l = 0; l < NLAYER; ++l) {
    k_attn<<<dim3(17, 8, NCHUNK), 256, 0, stream>>>(Qb, KB8, VB5, LP, APf);
    int nl = l + 1;
    int do_qkv = (nl < NLAYER) ? 1 : 0;
    const float* qw = qkv_w + (size_t)(do_qkv ? nl : 0) * 96 * 32;
    const float* qb = qkv_b + (size_t)(do_qkv ? nl : 0) * 96;
    k_fused<<<(LL + RB - 1) / RB, 256, 0, stream>>>(
        LP, APf, X, out_w + (size_t)l * 32 * 32, out_b + (size_t)l * 32,
        ln1_g + (size_t)l * 32, ln1_b + (size_t)l * 32,
        W1B + (size_t)l * FFD * 32, ff1_b + (size_t)l * FFD,
        W2B + (size_t)l * FFD * 32, ff2_b + (size_t)l * 32,
        ln2_g + (size_t)l * 32, ln2_b + (size_t)l * 32,
        qw, qb, Qb, KB8, VB5, do_qkv, cls_w, cls_b, (float*)d_out);
  }
}

// Round 4
// 466.343 us; speedup vs baseline: 3.8379x; 1.1210x over previous
//
#include <hip/hip_runtime.h>
#include <hip/hip_bf16.h>
#include <math.h>

// Problem constants
#define SEQ 4096
#define LL  4097           // sequence + CLS
#define HDIM 32
#define FFD 2048
#define NLAYER 6
#define EPSLN 1e-5f
#define NCHUNK 8           // split-K chunks over keys (512 keys each, last 544)
#define KPAD 4128          // keys 0..4096 padded to 129*32
#define QROWS 4352         // 17 blocks * 4 waves * 64 queries
#define XROWS 4160         // LL rounded up for ffnA A-fragment reads
#define RT 64              // FFN row tile
#define FS 128             // FFN f-segment width
#define NSEG 8             // part2 segments

#if __has_builtin(__builtin_amdgcn_exp2f)
#define EXP2 __builtin_amdgcn_exp2f
#else
#define EXP2 exp2f
#endif

#define QSCALE 0.7213475204444817f   // 0.5 * log2(e)

typedef short bf16x8 __attribute__((ext_vector_type(8)));
typedef float f32x4 __attribute__((ext_vector_type(4)));

__device__ __forceinline__ unsigned short f2b(float f) {   // fp32 -> bf16 RNE
  unsigned int b = __float_as_uint(f);
  b += 0x7FFFu + ((b >> 16) & 1u);
  return (unsigned short)(b >> 16);
}

__device__ __forceinline__ unsigned int pk_bf16(float a, float b) {
  __hip_bfloat162 h = __float22bfloat162_rn(make_float2(a, b));
  return *(unsigned int*)&h;
}

// Buffers:
//  Qb  [QROWS][32]  bf16, pre-scaled by QSCALE (pad rows zero)
//  KB8 [8][KPAD][8] bf16 — head h's K dims at slots (4h+d)&7; sibling head's
//      4 slots + pad rows zeroed once in k_init.
//  VB5 [8][5][KPAD] bf16, rows 0..3 = V dims (permuted key order), row 4 =
//      validity. Key permutation within 32-blocks: pos = ((w&15)<<1) | (w>>4)
//      — designed so pk(exp(S[k]), exp(S[k+16])) is directly the PV B-frag.
//  LP[(c*8+h)*LL+q] float, AP4[(c*8+h)*LL+q] float4 — split-K partials.
//  Xb  [XROWS][32] bf16 — post-LN1 X, ffnA's GEMM1 A operand.

// wave-level qkv projection + bf16 stores. y = this thread's (row,ch) value.
__device__ __forceinline__ void qkv_wave(float y, int row, bool ok, int lane,
    const float* __restrict__ qw, const float* __restrict__ qb,
    unsigned short* __restrict__ Qb, unsigned short* __restrict__ KB8,
    unsigned short* __restrict__ VB5) {
  int ch = lane & 31;
  float xv[32];
#pragma unroll
  for (int k = 0; k < 32; ++k) xv[k] = __shfl(y, (lane & 32) + k, 64);
#pragma unroll
  for (int t3 = 0; t3 < 3; ++t3) {
    int cc = t3 * 32 + ch;
    float acc = qb[cc];
#pragma unroll
    for (int k = 0; k < 32; ++k) acc = fmaf(xv[k], qw[cc * 32 + k], acc);
    if (ok) {
      int h = ch >> 2;
      if (t3 == 0) {
        Qb[(size_t)row * 32 + ch] = f2b(QSCALE * acc);
      } else if (t3 == 1) {
        KB8[((size_t)h * KPAD + row) * 8 + (ch & 7)] = f2b(acc);
      } else {
        int w = row & 31;
        int pos = ((w & 15) << 1) | (w >> 4);
        VB5[((size_t)h * 5 + (ch & 3)) * KPAD + (row & ~31) + pos] = f2b(acc);
      }
    }
  }
}

// ---- init: weight cvt + pad zeroing + embed + layer-0 qkv (all disjoint) ---
__global__ __launch_bounds__(256) void k_init(const float* __restrict__ data,
    const float* __restrict__ lin_w, const float* __restrict__ lin_b,
    const float* __restrict__ qkv_w, const float* __restrict__ qkv_b,
    const float* __restrict__ ff1_w, const float* __restrict__ ff2_w,
    float* __restrict__ X, unsigned short* __restrict__ Xb,
    unsigned short* __restrict__ Qb,
    unsigned short* __restrict__ KB8, unsigned short* __restrict__ VB5,
    unsigned short* __restrict__ W1B, unsigned short* __restrict__ W2B) {
  int gid = blockIdx.x * 256 + threadIdx.x;
  int gsz = gridDim.x * 256;
  const int NW = NLAYER * FFD * 32;
  for (int i = gid; i < NW; i += gsz) {
    W1B[i] = f2b(ff1_w[i]);
    W2B[i] = f2b(ff2_w[i]);
  }
  for (int i = gid; i < (QROWS - LL) * 32; i += gsz)
    Qb[(size_t)LL * 32 + i] = 0;                    // query pad rows
  for (int i = gid; i < (XROWS - LL) * 32; i += gsz)
    Xb[(size_t)LL * 32 + i] = 0;                    // ffnA pad rows
  for (int i = gid; i < 8 * (KPAD - LL) * 8; i += gsz) {
    int hh = i / ((KPAD - LL) * 8);
    int rem = i % ((KPAD - LL) * 8);
    KB8[((size_t)hh * KPAD + LL) * 8 + rem] = 0;    // K pad rows
  }
  for (int i = gid; i < 8 * LL * 4; i += gsz) {     // K unwritten slots
    int hh = i / (LL * 4);
    int rem = i % (LL * 4);
    int rr = rem >> 2, s = rem & 3;
    int slot = (hh & 1) ? s : 4 + s;
    KB8[((size_t)hh * KPAD + rr) * 8 + slot] = 0;
  }
  for (int i = gid; i < 8 * 5 * KPAD; i += gsz) {
    int col = i % KPAD;
    int dd = (i / KPAD) % 5;
    if (dd == 4) {
      int key = (col & ~31) + ((col & 1) << 4) + ((col & 31) >> 1);
      VB5[i] = (key <= 4096) ? 0x3F80 : 0;          // validity row
    } else if (col > 4096) {
      VB5[i] = 0;                                   // pad-key V entries
    }
  }
  // embed + layer-0 qkv: wave items, 2 rows each
  int wave = threadIdx.x >> 6, lane = threadIdx.x & 63;
  int r = lane >> 5, ch = lane & 31;
  unsigned wgid = blockIdx.x * 4 + wave;
  for (unsigned it = wgid; it < 2049; it += gridDim.x * 4) {
    int row = it * 2 + r;
    bool ok = row < LL;
    float val = 0.f;
    if (ok) {
      if (row == 0) {
        val = -1.0f;
      } else {
        int s = row - 1;
        float ts = data[s * 3 + 0];
        float f0 = data[s * 3 + 1];
        float f1 = data[s * 3 + 2];
        float lin = f0 * lin_w[ch * 2 + 0] + f1 * lin_w[ch * 2 + 1] + lin_b[ch];
        lin = fmaxf(lin, 0.0f);
        int tsi = (int)(ts / 100.0f);
        int j = ch >> 1;
        float aj = (float)(2 * j) * (float)(-0.28782313662425575);
        float divj = (float)exp((double)aj);
        float ang = (float)tsi * divj;
        float pe = (ch & 1) ? cosf(ang) : sinf(ang);
        val = lin + pe;
      }
      X[(size_t)row * HDIM + ch] = val;
    }
    qkv_wave(val, row, ok, lane, qkv_w, qkv_b, Qb, KB8, VB5);
  }
}

// ---- attention, swapped-operand MFMA: NO LDS, no transpose -----------------
// mfma(K, Q) gives S^T: lane = q-col (l16), regs = keys quad*4+reg (+16 in
// s1). pk(exp(s0[r]), exp(s1[r])) lands keys exactly in VB5's permuted
// order at contraction positions quad*8+{2r,2r+1} -> the packed dwords ARE
// the PV B-fragment in-lane. grid (17, 8, NCHUNK); wave owns 64 queries.
__global__ __launch_bounds__(256, 4) void k_attn(
    const unsigned short* __restrict__ Qb, const unsigned short* __restrict__ KB8,
    const unsigned short* __restrict__ VB5, float* __restrict__ LP,
    float4* __restrict__ AP4) {
  int tid = threadIdx.x;
  int wave = tid >> 6, lane = tid & 63;
  int l16 = lane & 15, quad = lane >> 4;
  int h = blockIdx.y, c = blockIdx.z;
  int qs = blockIdx.x * 4 + wave;
  if (qs >= 65) return;                  // wave-uniform exit, no barriers used
  int q0 = qs * 64;
  int kb0 = c * 512;
  int nkb = (c == NCHUNK - 1) ? 17 : 16;

  const unsigned short* KBh = KB8 + (size_t)h * KPAD * 8;
  const unsigned short* VBh = VB5 + (size_t)h * 5 * KPAD;
  const bool kl = (quad == (h >> 1));   // only this quad carries K data
  const bool vl = (l16 < 5);            // only V rows 0..4 are nonzero

  bf16x8 aq[4];                          // Q tiles: B-operand (row = l16 = q)
#pragma unroll
  for (int t = 0; t < 4; ++t)
    aq[t] = *(const bf16x8*)&Qb[(size_t)(q0 + t * 16 + l16) * 32 + quad * 8];

  const bf16x8 zb = {0, 0, 0, 0, 0, 0, 0, 0};
  f32x4 acc0[4], acc1[4];
#pragma unroll
  for (int t = 0; t < 4; ++t) {
    acc0[t] = (f32x4){0.f, 0.f, 0.f, 0.f};
    acc1[t] = (f32x4){0.f, 0.f, 0.f, 0.f};
  }

  auto step = [&](int k0, f32x4* acc) {
    bf16x8 bk0 = kl ? *(const bf16x8*)&KBh[(size_t)(k0 + l16) * 8] : zb;
    bf16x8 bk1 = kl ? *(const bf16x8*)&KBh[(size_t)(k0 + 16 + l16) * 8] : zb;
    bf16x8 bv = vl ? *(const bf16x8*)&VBh[(size_t)l16 * KPAD + k0 + quad * 8]
                   : zb;
    f32x4 z = {0.f, 0.f, 0.f, 0.f};
    unsigned pf[4][4];                   // packed P fragments (bf16x8 each)
#pragma unroll
    for (int t = 0; t < 4; ++t) {
      f32x4 s0 = __builtin_amdgcn_mfma_f32_16x16x32_bf16(bk0, aq[t], z, 0, 0, 0);
      f32x4 s1 = __builtin_amdgcn_mfma_f32_16x16x32_bf16(bk1, aq[t], z, 0, 0, 0);
#pragma unroll
      for (int reg = 0; reg < 4; ++reg)
        pf[t][reg] = pk_bf16(EXP2(s0[reg]), EXP2(s1[reg]));
    }
#pragma unroll
    for (int t = 0; t < 4; ++t) {
      bf16x8 pb = *(const bf16x8*)&pf[t][0];
      acc[t] = __builtin_amdgcn_mfma_f32_16x16x32_bf16(bv, pb, acc[t], 0, 0, 0);
    }
  };

  int kb = 0;
  for (; kb + 2 <= nkb; kb += 2) {
    step(kb0 + kb * 32, acc0);
    step(kb0 + (kb + 1) * 32, acc1);
  }
  if (kb < nkb) step(kb0 + kb * 32, acc0);

  // Output: lane holds O^T rows d=quad*4+reg for q=l16 of each tile.
  // quad0: d0..3 -> one coalesced float4; quad1 reg0: d4 = L (validity sum).
  size_t base = ((size_t)c * 8 + h) * LL;
#pragma unroll
  for (int t = 0; t < 4; ++t) {
    f32x4 a = acc0[t] + acc1[t];
    int q = q0 + t * 16 + l16;
    if (q < LL) {
      if (quad == 0) {
        AP4[base + q] = make_float4(a[0], a[1], a[2], a[3]);
      } else if (quad == 1) {
        LP[base + q] = a[0];
      }
    }
  }
}

// ------- fused: sum split-K partials + o-proj + residual + LN1 --------------
__global__ __launch_bounds__(256) void k_oproj(const float* __restrict__ LP,
    const float4* __restrict__ AP, float* __restrict__ x,
    unsigned short* __restrict__ Xb,
    const float* __restrict__ ow, const float* __restrict__ ob,
    const float* __restrict__ g, const float* __restrict__ bln) {
  int tid = threadIdx.x;
  int r = tid >> 5, ch = tid & 31;
  int row = blockIdx.x * 8 + r;
  __shared__ float os[8][32];
  bool ok = row < LL;
  if (ok) {
    int h = ch >> 2, d = ch & 3;
    float L = 0.f, A = 0.f;
#pragma unroll
    for (int c = 0; c < NCHUNK; ++c) {
      size_t idx = ((size_t)c * 8 + h) * LL + row;
      L += LP[idx];
      A += ((const float*)&AP[idx])[d];
    }
    os[r][ch] = A / L;
  } else {
    os[r][ch] = 0.f;
  }
  __syncthreads();
  float acc = 0.f;
#pragma unroll
  for (int k = 0; k < 32; ++k) acc = fmaf(os[r][k], ow[ch * 32 + k], acc);
  float val = ok ? (x[(size_t)row * HDIM + ch] + acc + ob[ch]) : 0.f;
  float mean = val;
#pragma unroll
  for (int off = 16; off > 0; off >>= 1) mean += __shfl_xor(mean, off, 32);
  mean *= (1.f / 32.f);
  float d2 = val - mean;
  float var = d2 * d2;
#pragma unroll
  for (int off = 16; off > 0; off >>= 1) var += __shfl_xor(var, off, 32);
  var *= (1.f / 32.f);
  float y = d2 / sqrtf(var + EPSLN) * g[ch] + bln[ch];
  if (ok) {
    x[(size_t)row * HDIM + ch] = y;
    Xb[(size_t)row * HDIM + ch] = f2b(y);
  }
}

// ---------------- FFN part A via MFMA bf16, 2 f-segments per block ----------
__global__ __launch_bounds__(256) void k_ffnA(
    const unsigned short* __restrict__ Xb,
    const unsigned short* __restrict__ w1b, const float* __restrict__ b1,
    const unsigned short* __restrict__ w2b, float* __restrict__ part2) {
  __shared__ unsigned short Fsb[RT * 136];
  int tid = threadIdx.x;
  int r0 = blockIdx.x * RT;
  int wave = tid >> 6, lane = tid & 63;
  int l16 = lane & 15, quad = lane >> 4;
  int m0 = wave * 16;

  bf16x8 a1 = *(const bf16x8*)&Xb[(size_t)(r0 + m0 + l16) * 32 + quad * 8];
  f32x4 acc[2] = {{0.f, 0.f, 0.f, 0.f}, {0.f, 0.f, 0.f, 0.f}};

#pragma unroll
  for (int sg = 0; sg < 2; ++sg) {
    int f0 = (blockIdx.y * 2 + sg) * FS;
    f32x4 c1[8];
#pragma unroll
    for (int t = 0; t < 8; ++t) {
      bf16x8 b =
          *(const bf16x8*)&w1b[(size_t)(f0 + t * 16 + l16) * 32 + quad * 8];
      f32x4 z = {0.f, 0.f, 0.f, 0.f};
      c1[t] = __builtin_amdgcn_mfma_f32_16x16x32_bf16(a1, b, z, 0, 0, 0);
    }
    if (sg) __syncthreads();   // prev segment's Fsb reads complete
#pragma unroll
    for (int t = 0; t < 8; ++t) {
      float bb = b1[f0 + t * 16 + l16];
#pragma unroll
      for (int reg = 0; reg < 4; ++reg) {
        float v = fmaxf(c1[t][reg] + bb, 0.f);
        int rrow = m0 + quad * 4 + reg;
        Fsb[rrow * 136 + t * 16 + l16] = f2b(v);
      }
    }
    __syncthreads();
#pragma unroll
    for (int kt = 0; kt < 4; ++kt) {
      bf16x8 a2 = *(const bf16x8*)&Fsb[(m0 + l16) * 136 + kt * 32 + quad * 8];
#pragma unroll
      for (int u = 0; u < 2; ++u) {
        bf16x8 b = *(const bf16x8*)&w2b[(size_t)(u * 16 + l16) * FFD + f0 +
                                        kt * 32 + quad * 8];
        acc[u] = __builtin_amdgcn_mfma_f32_16x16x32_bf16(a2, b, acc[u], 0, 0, 0);
      }
    }
  }
#pragma unroll
  for (int u = 0; u < 2; ++u) {
#pragma unroll
    for (int reg = 0; reg < 4; ++reg) {
      int rrow = r0 + m0 + quad * 4 + reg;
      if (rrow < LL)
        part2[((size_t)blockIdx.y * LL + rrow) * HDIM + u * 16 + l16] =
            acc[u][reg];
    }
  }
}

// ------ FFN part B: combine + residual + LN2 + next qkv (bf16) + final ------
__global__ __launch_bounds__(256) void k_ffnB_qkv(float* __restrict__ x,
    const float* __restrict__ part2, const float* __restrict__ b2,
    const float* __restrict__ g, const float* __restrict__ bln,
    const float* __restrict__ qw, const float* __restrict__ qb,
    unsigned short* __restrict__ Qb, unsigned short* __restrict__ KB8,
    unsigned short* __restrict__ VB5, int do_qkv,
    const float* __restrict__ cw, const float* __restrict__ cb,
    float* __restrict__ out) {
  int tid = threadIdx.x;
  int wave = tid >> 6, lane = tid & 63;
  int r = lane >> 5, ch = lane & 31;
  int row = blockIdx.x * 8 + wave * 2 + r;
  bool ok = row < LL;
  float s = 0.f;
  if (ok) {
#pragma unroll
    for (int q = 0; q < NSEG; ++q)
      s += part2[((size_t)q * LL + row) * HDIM + ch];
  }
  float val = ok ? (x[(size_t)row * HDIM + ch] + s + b2[ch]) : 0.f;
  float mean = val;
#pragma unroll
  for (int off = 16; off > 0; off >>= 1) mean += __shfl_xor(mean, off, 32);
  mean *= (1.f / 32.f);
  float d = val - mean;
  float var = d * d;
#pragma unroll
  for (int off = 16; off > 0; off >>= 1) var += __shfl_xor(var, off, 32);
  var *= (1.f / 32.f);
  float y = d / sqrtf(var + EPSLN) * g[ch] + bln[ch];
  if (ok) x[(size_t)row * HDIM + ch] = y;
  if (!do_qkv) {
    if (blockIdx.x == 0 && wave == 0 && r == 0) {
      float t = y * cw[ch];
#pragma unroll
      for (int off = 16; off > 0; off >>= 1) t += __shfl_xor(t, off, 32);
      if (ch == 0) {
        float z = t + cb[0];
        out[0] = 1.f / (1.f + expf(-z));
      }
    }
    return;
  }
  qkv_wave(y, row, ok, lane, qw, qb, Qb, KB8, VB5);
}

extern "C" void kernel_launch(void* const* d_in, const int* in_sizes, int n_in,
                              void* d_out, int out_size, void* d_ws,
                              size_t ws_size, hipStream_t stream) {
  const float* data  = (const float*)d_in[0];
  const float* lin_w = (const float*)d_in[1];
  const float* lin_b = (const float*)d_in[2];
  const float* qkv_w = (const float*)d_in[3];
  const float* qkv_b = (const float*)d_in[4];
  const float* out_w = (const float*)d_in[5];
  const float* out_b = (const float*)d_in[6];
  const float* ln1_g = (const float*)d_in[7];
  const float* ln1_b = (const float*)d_in[8];
  const float* ff1_w = (const float*)d_in[9];
  const float* ff1_b = (const float*)d_in[10];
  const float* ff2_w = (const float*)d_in[11];
  const float* ff2_b = (const float*)d_in[12];
  const float* ln2_g = (const float*)d_in[13];
  const float* ln2_b = (const float*)d_in[14];
  const float* cls_w = (const float*)d_in[15];
  const float* cls_b = (const float*)d_in[16];

  char* wsb = (char*)d_ws;
  float* X = (float*)wsb;                               // LL*32 fp32
  unsigned short* Xb  = (unsigned short*)(X + (size_t)LL * 32);
  unsigned short* Qb  = Xb + (size_t)XROWS * 32;
  unsigned short* KB8 = Qb + (size_t)QROWS * 32;        // 8*KPAD*8
  unsigned short* VB5 = KB8 + (size_t)8 * KPAD * 8;     // 8*5*KPAD
  unsigned short* W1B = VB5 + (size_t)8 * 5 * KPAD;     // NL*FFD*32
  unsigned short* W2B = W1B + (size_t)NLAYER * FFD * 32;
  float4* AP = (float4*)(((size_t)(W2B + (size_t)NLAYER * FFD * 32) + 15) &
                         ~(size_t)15);                  // NCHUNK*8*LL float4
  float* LP = (float*)(AP + (size_t)NCHUNK * 8 * LL);
  float* PART2 = (float*)AP;   // aliased; AP dead once oproj has run

  const int NROWB = (LL + 7) / 8;                       // 513

  k_init<<<1024, 256, 0, stream>>>(data, lin_w, lin_b, qkv_w, qkv_b,
                                   ff1_w, ff2_w, X, Xb, Qb, KB8, VB5,
                                   W1B, W2B);
  for (int l = 0; l < NLAYER; ++l) {
    k_attn<<<dim3(17, 8, NCHUNK), 256, 0, stream>>>(Qb, KB8, VB5, LP, AP);
    k_oproj<<<NROWB, 256, 0, stream>>>(
        LP, AP, X, Xb, out_w + (size_t)l * 32 * 32, out_b + (size_t)l * 32,
        ln1_g + (size_t)l * 32, ln1_b + (size_t)l * 32);
    k_ffnA<<<dim3((LL + RT - 1) / RT, NSEG), 256, 0, stream>>>(
        Xb, W1B + (size_t)l * FFD * 32, ff1_b + (size_t)l * FFD,
        W2B + (size_t)l * FFD * 32, PART2);
    int nl = l + 1;
    int do_qkv = (nl < NLAYER) ? 1 : 0;
    const float* qw = qkv_w + (size_t)(do_qkv ? nl : 0) * 96 * 32;
    const float* qb = qkv_b + (size_t)(do_qkv ? nl : 0) * 96;
    k_ffnB_qkv<<<NROWB, 256, 0, stream>>>(
        X, PART2, ff2_b + (size_t)l * 32,
        ln2_g + (size_t)l * 32, ln2_b + (size_t)l * 32,
        qw, qb, Qb, KB8, VB5, do_qkv, cls_w, cls_b, (float*)d_out);
  }
}